// Round 11
// baseline (549.711 us; speedup 1.0000x reference)
//
#include <hip/hip_runtime.h>

#define NN 100000
#define DD 128
#define RR 8
#define NB1 98                // ceil(NN/1024)
#define ECAP 2048             // per-block LDS edge-index cap (32 dst-segs, ~512 edges avg)

typedef unsigned short u16;
typedef __bf16 bf16x8 __attribute__((ext_vector_type(8)));
typedef float f32x4 __attribute__((ext_vector_type(4)));

__device__ __forceinline__ u16 f2bf(float f){
    union { float f; unsigned u; } v; v.f = f;
    unsigned r = v.u + 0x7fffu + ((v.u >> 16) & 1u);
    return (u16)(r >> 16);
}
__device__ __forceinline__ float bf2f(u16 h){
    union { unsigned u; float f; } v; v.u = ((unsigned)h) << 16; return v.f;
}
__device__ __forceinline__ unsigned cvtpk(float lo, float hi){
    unsigned r;
    asm("v_cvt_pk_bf16_f32 %0, %1, %2" : "=v"(r) : "v"(lo), "v"(hi));
    return r;
}
__device__ __forceinline__ bf16x8 cvt8(float4 a, float4 b){
    union { unsigned u[4]; bf16x8 v; } o;
    o.u[0] = cvtpk(a.x, a.y); o.u[1] = cvtpk(a.z, a.w);
    o.u[2] = cvtpk(b.x, b.y); o.u[3] = cvtpk(b.z, b.w);
    return o.v;
}
__device__ __forceinline__ float ftanh(float x){
    float e = __expf(2.0f * x);
    return 1.0f - 2.0f / (e + 1.0f);
}
__device__ __forceinline__ bf16x8 ldv(const u16* p){
    return *reinterpret_cast<const bf16x8*>(p);
}
__device__ __forceinline__ void gload_lds16(const void* g, void* l){
    __builtin_amdgcn_global_load_lds(
        (const __attribute__((address_space(1))) void*)g,
        (__attribute__((address_space(3))) void*)l, 16, 0, 0);
}

// ---- prep: transpose weights to out-major bf16 ----
// WT[9][128][128]: WT[r][o][d] = W_rel[r][d][o]; WT[8] = loop_w^T
// W1t[256][256]: W1t[n][k] = W1[k][n];  W2t[128][384]: W2t[n][k] = W2[k][n]
__global__ void k_prep_w(const float* __restrict__ Wrel, const float* __restrict__ loopw,
                         const float* __restrict__ W1, const float* __restrict__ W2,
                         u16* __restrict__ WT, u16* __restrict__ W1t, u16* __restrict__ W2t){
    int tid = blockIdx.x * 256 + threadIdx.x;   // grid 1024*256 = 262144 exactly
    if (tid < 131072) {
        int r = tid >> 14, rem = tid & 16383, d = rem >> 7, o = rem & 127;
        WT[(r * 128 + o) * 128 + d] = f2bf(Wrel[tid]);
    } else if (tid < 147456) {
        int i = tid - 131072, d = i >> 7, o = i & 127;
        WT[(8 * 128 + o) * 128 + d] = f2bf(loopw[i]);
    } else if (tid < 212992) {
        int i = tid - 147456, k = i >> 8, n2 = i & 255;
        W1t[n2 * 256 + k] = f2bf(W1[i]);
    } else {
        int i = tid - 212992, k = i >> 7, n2 = i & 127;
        W2t[n2 * 384 + k] = f2bf(W2[i]);
    }
}

// ---- CSR build over dst only (100K segments, avg degree 16) ----
__global__ void k_count(const int* __restrict__ et, const int* __restrict__ dst,
                        const int* __restrict__ src,
                        int* __restrict__ cnt, int* __restrict__ gidx, int E){
    int e = blockIdx.x * 256 + threadIdx.x;
    if (e < E){
        gidx[e] = et[e] * NN + src[e];     // gather row in y
        atomicAdd(&cnt[dst[e]], 1);
    }
}

__global__ void k_scan1(const int* __restrict__ cnt, int* __restrict__ Off, int* __restrict__ bsum){
    __shared__ int lds[256];
    int t = threadIdx.x;
    int i0 = blockIdx.x * 1024 + t * 4;
    int c0 = (i0 + 0 < NN) ? cnt[i0 + 0] : 0;
    int c1 = (i0 + 1 < NN) ? cnt[i0 + 1] : 0;
    int c2 = (i0 + 2 < NN) ? cnt[i0 + 2] : 0;
    int c3 = (i0 + 3 < NN) ? cnt[i0 + 3] : 0;
    int s = c0 + c1 + c2 + c3;
    lds[t] = s; __syncthreads();
    for (int off = 1; off < 256; off <<= 1){
        int v = (t >= off) ? lds[t - off] : 0;
        __syncthreads();
        lds[t] += v;
        __syncthreads();
    }
    int excl = lds[t] - s;
    if (i0 + 0 < NN) Off[i0 + 0] = excl; excl += c0;
    if (i0 + 1 < NN) Off[i0 + 1] = excl; excl += c1;
    if (i0 + 2 < NN) Off[i0 + 2] = excl; excl += c2;
    if (i0 + 3 < NN) Off[i0 + 3] = excl;
    if (t == 255) bsum[blockIdx.x] = lds[255];
}

__global__ void k_scan2(int* __restrict__ bsum){
    __shared__ int lds[1024];
    int t = threadIdx.x;
    int v = (t < NB1) ? bsum[t] : 0;
    lds[t] = v; __syncthreads();
    for (int off = 1; off < 1024; off <<= 1){
        int u = (t >= off) ? lds[t - off] : 0;
        __syncthreads();
        lds[t] += u;
        __syncthreads();
    }
    if (t < NB1) bsum[t] = lds[t] - v;
}

__global__ void k_scan3(int* __restrict__ Off, const int* __restrict__ bsum,
                        int* __restrict__ cursor, int E){
    int base = bsum[blockIdx.x];
    int t = threadIdx.x;
    int i0 = blockIdx.x * 1024 + t * 4;
    #pragma unroll
    for (int j = 0; j < 4; ++j){
        int i = i0 + j;
        if (i < NN){ int v = Off[i] + base; Off[i] = v; cursor[i] = v; }
    }
    if (blockIdx.x == 0 && t == 0) Off[NN] = E;
}

__global__ void k_scatter(const int* __restrict__ dst, const int* __restrict__ gidx,
                          int* __restrict__ cursor, int* __restrict__ esrc, int E){
    int e = blockIdx.x * 256 + threadIdx.x;
    if (e < E){
        int pos = atomicAdd(&cursor[dst[e]], 1);
        esrc[pos] = gidx[e];
    }
}

// ---- k_y: y[r] = x @ W_r for r=0..8 (8 relations + loop_w), barrier-free ----
// 64-row tile, 512 threads = 8 waves; x rows in registers (f32 load + cvt_pk);
// wave w owns output cols [16w,16w+16). 144 MFMA/block, no LDS.
__global__ __launch_bounds__(512) void k_y(
    const float* __restrict__ x, const u16* __restrict__ WT, u16* __restrict__ y)
{
    const int tid = threadIdx.x;
    const int w = tid >> 6;
    const int lane = tid & 63;
    const int l15 = lane & 15;
    const int l4 = lane >> 4;
    const int kof = l4 * 8;
    const int b64 = blockIdx.x * 64;

    bf16x8 xr[4][4];
    #pragma unroll
    for (int mi = 0; mi < 4; ++mi){
        int rr = b64 + mi * 16 + l15; if (rr >= NN) rr = NN - 1;
        #pragma unroll
        for (int kc = 0; kc < 4; ++kc){
            const float* px = x + (size_t)rr * DD + kc * 32 + kof;
            xr[mi][kc] = cvt8(*reinterpret_cast<const float4*>(px),
                              *reinterpret_cast<const float4*>(px + 4));
        }
    }

    for (int r = 0; r < 9; ++r){
        f32x4 acc[4];
        #pragma unroll
        for (int mi = 0; mi < 4; ++mi)
            #pragma unroll
            for (int q = 0; q < 4; ++q) acc[mi][q] = 0.f;
        const u16* B = WT + r * (DD * DD);
        #pragma unroll
        for (int kc = 0; kc < 4; ++kc){
            bf16x8 wv = ldv(B + (w * 16 + l15) * DD + kc * 32 + kof);
            #pragma unroll
            for (int mi = 0; mi < 4; ++mi)
                acc[mi] = __builtin_amdgcn_mfma_f32_16x16x32_bf16(xr[mi][kc], wv, acc[mi], 0, 0, 0);
        }
        int col = w * 16 + l15;
        #pragma unroll
        for (int mi = 0; mi < 4; ++mi){
            #pragma unroll
            for (int q = 0; q < 4; q += 2){
                int row0 = b64 + mi * 16 + l4 * 4 + q;
                unsigned p = cvtpk(acc[mi][q], acc[mi][q + 1]);
                if (row0 < NN)     y[((size_t)r * NN + row0) * DD + col] = (u16)(p & 0xffffu);
                if (row0 + 1 < NN) y[((size_t)r * NN + row0 + 1) * DD + col] = (u16)(p >> 16);
            }
        }
    }
}

// ---- k_gath: msg[i] = sum_{e:dst=i} y[gidx_e] + y[8NN+i] (self) + rel_bias ----
// 32 dst-segments/block (grid 3125 exact); Off+edge-list staged in LDS;
// writes msg IN PLACE over y8 (each y8 row read only by its own segment).
__global__ __launch_bounds__(256) void k_gath(
    const u16* __restrict__ y, const int* __restrict__ Off,
    const int* __restrict__ esrc, const float* __restrict__ relb,
    u16* __restrict__ msg)
{
    __shared__ int offs[33];
    __shared__ int eidx[ECAP];
    const int tid = threadIdx.x;
    const int s0 = blockIdx.x * 32;
    if (tid < 33) offs[tid] = Off[s0 + tid];
    __syncthreads();
    const int base = offs[0];
    const int tot = offs[32] - base;
    const bool inlds = (tot <= ECAP);
    if (inlds){
        for (int i = tid; i < tot; i += 256) eidx[i] = esrc[base + i];
    }
    __syncthreads();

    const int hw = tid >> 5;
    const int lid = tid & 31;
    const int c = lid * 4;
    const float rb0 = relb[c], rb1 = relb[c+1], rb2 = relb[c+2], rb3 = relb[c+3];

    #pragma unroll
    for (int j = 0; j < 4; ++j){
        const int sj = hw * 4 + j;
        const int node = s0 + sj;
        const int lo = offs[sj] - base;
        const int hi = offs[sj + 1] - base;
        // self-loop row + bias
        ushort4 v8 = *reinterpret_cast<const ushort4*>(y + ((size_t)8 * NN + node) * DD + c);
        float a0 = bf2f(v8.x) + rb0, a1 = bf2f(v8.y) + rb1;
        float a2 = bf2f(v8.z) + rb2, a3 = bf2f(v8.w) + rb3;
        int e = lo;
        if (inlds){
            for (; e + 4 <= hi; e += 4){
                int i0 = eidx[e], i1 = eidx[e+1], i2 = eidx[e+2], i3 = eidx[e+3];
                ushort4 v0 = *reinterpret_cast<const ushort4*>(y + (size_t)i0 * DD + c);
                ushort4 v1 = *reinterpret_cast<const ushort4*>(y + (size_t)i1 * DD + c);
                ushort4 v2 = *reinterpret_cast<const ushort4*>(y + (size_t)i2 * DD + c);
                ushort4 v3 = *reinterpret_cast<const ushort4*>(y + (size_t)i3 * DD + c);
                a0 += bf2f(v0.x) + bf2f(v1.x) + bf2f(v2.x) + bf2f(v3.x);
                a1 += bf2f(v0.y) + bf2f(v1.y) + bf2f(v2.y) + bf2f(v3.y);
                a2 += bf2f(v0.z) + bf2f(v1.z) + bf2f(v2.z) + bf2f(v3.z);
                a3 += bf2f(v0.w) + bf2f(v1.w) + bf2f(v2.w) + bf2f(v3.w);
            }
            for (; e < hi; ++e){
                int i = eidx[e];
                ushort4 v = *reinterpret_cast<const ushort4*>(y + (size_t)i * DD + c);
                a0 += bf2f(v.x); a1 += bf2f(v.y); a2 += bf2f(v.z); a3 += bf2f(v.w);
            }
        } else {
            for (; e < hi; ++e){
                int i = esrc[base + e];
                ushort4 v = *reinterpret_cast<const ushort4*>(y + (size_t)i * DD + c);
                a0 += bf2f(v.x); a1 += bf2f(v.y); a2 += bf2f(v.z); a3 += bf2f(v.w);
            }
        }
        unsigned p0 = cvtpk(a0, a1), p1 = cvtpk(a2, a3);
        uint2 ov; ov.x = p0; ov.y = p1;
        *reinterpret_cast<uint2*>(msg + (size_t)node * DD + c) = ov;   // in-place over y8
    }
}

// ---- k_fused: pure 2-layer MLP over [x | msg] ----
// 64-row tile, 8 waves. msg tile via swizzled DMA (verified r7/8 pattern);
// x frags in registers (f32 + cvt_pk). LDS: msgT[64][128] + mids[64][264]
// = 50176 B. Single staging exposure; 112 MFMA/wave.
__global__ __launch_bounds__(512, 2) void k_fused(
    const float* __restrict__ x, const u16* __restrict__ msg,
    const u16* __restrict__ W1t, const u16* __restrict__ W2t,
    const float* __restrict__ bb1, const float* __restrict__ bb2,
    float* __restrict__ out)
{
    __shared__ __align__(16) u16 smem[25088];
    u16 (*mids)[264] = (u16(*)[264])(smem + 8192);

    const int tid = threadIdx.x;
    const int w = tid >> 6;
    const int lane = tid & 63;
    const int l15 = lane & 15;
    const int l4 = lane >> 4;
    const int kof = l4 * 8;
    const int swz = (l15 & 7) << 3;
    const int b64 = blockIdx.x * 64;

    // DMA msg tile, swizzled source (both-sides involution, rule 21)
    #pragma unroll
    for (int is = 0; is < 2; ++is){
        int W = tid * 16 + is * 8192;             // LDS byte
        int row = W >> 8;
        int srow = (b64 + row < NN) ? row : 0;
        int inrow = (W & 255) ^ ((row & 7) << 4);
        const char* src = (const char*)(msg + (size_t)(b64 + srow) * DD) + inrow;
        gload_lds16(src, (char*)smem + W);
    }
    // x frags -> registers
    bf16x8 xr[4][4];
    #pragma unroll
    for (int mi = 0; mi < 4; ++mi){
        int rr = b64 + mi * 16 + l15; if (rr >= NN) rr = NN - 1;
        #pragma unroll
        for (int kc = 0; kc < 4; ++kc){
            const float* px = x + (size_t)rr * DD + kc * 32 + kof;
            xr[mi][kc] = cvt8(*reinterpret_cast<const float4*>(px),
                              *reinterpret_cast<const float4*>(px + 4));
        }
    }
    __syncthreads();   // msg tile in LDS

    // MLP1: mid = tanh([x|msg] @ W1 + b1); wave owns cols [32w,32w+32)
    f32x4 acc2[4][2];
    #pragma unroll
    for (int mi = 0; mi < 4; ++mi)
        #pragma unroll
        for (int nj = 0; nj < 2; ++nj)
            #pragma unroll
            for (int q = 0; q < 4; ++q) acc2[mi][nj][q] = 0.f;

    #pragma unroll
    for (int kc = 0; kc < 8; ++kc){
        bf16x8 a[4];
        #pragma unroll
        for (int mi = 0; mi < 4; ++mi)
            a[mi] = (kc < 4) ? xr[mi][kc]
                             : ldv(smem + (mi * 16 + l15) * 128 + (((kc - 4) * 32 + kof) ^ swz));
        #pragma unroll
        for (int nj = 0; nj < 2; ++nj){
            int n2 = w * 32 + nj * 16 + l15;
            bf16x8 wv = ldv(W1t + n2 * 256 + kc * 32 + kof);
            #pragma unroll
            for (int mi = 0; mi < 4; ++mi)
                acc2[mi][nj] = __builtin_amdgcn_mfma_f32_16x16x32_bf16(a[mi], wv, acc2[mi][nj], 0, 0, 0);
        }
    }
    // mids region disjoint from msgT -> no barrier before writes
    #pragma unroll
    for (int nj = 0; nj < 2; ++nj){
        int col = w * 32 + nj * 16 + l15;
        float bv = bb1[col];
        #pragma unroll
        for (int mi = 0; mi < 4; ++mi)
            #pragma unroll
            for (int q = 0; q < 4; ++q)
                mids[mi * 16 + l4 * 4 + q][col] = f2bf(ftanh(acc2[mi][nj][q] + bv));
    }
    __syncthreads();

    // MLP2: out = [x|mid] @ W2 + b2; wave owns cols [16w,16w+16)
    f32x4 acc3[4];
    #pragma unroll
    for (int mi = 0; mi < 4; ++mi)
        #pragma unroll
        for (int q = 0; q < 4; ++q) acc3[mi][q] = 0.f;

    #pragma unroll
    for (int kc = 0; kc < 12; ++kc){
        bf16x8 a[4];
        #pragma unroll
        for (int mi = 0; mi < 4; ++mi)
            a[mi] = (kc < 4) ? xr[mi][kc]
                             : ldv(&mids[mi * 16 + l15][(kc - 4) * 32 + kof]);
        bf16x8 wv = ldv(W2t + (w * 16 + l15) * 384 + kc * 32 + kof);
        #pragma unroll
        for (int mi = 0; mi < 4; ++mi)
            acc3[mi] = __builtin_amdgcn_mfma_f32_16x16x32_bf16(a[mi], wv, acc3[mi], 0, 0, 0);
    }

    {
        int col = w * 16 + l15;
        float bv = bb2[col];
        #pragma unroll
        for (int mi = 0; mi < 4; ++mi)
            #pragma unroll
            for (int q = 0; q < 4; ++q){
                int row = b64 + mi * 16 + l4 * 4 + q;
                if (row < NN)
                    __builtin_nontemporal_store(acc3[mi][q] + bv,
                        &out[(size_t)row * DD + col]);
            }
    }
}

extern "C" void kernel_launch(void* const* d_in, const int* in_sizes, int n_in,
                              void* d_out, int out_size, void* d_ws, size_t ws_size,
                              hipStream_t stream){
    const float* x    = (const float*)d_in[0];
    const int*   src  = (const int*)d_in[1];
    const int*   dst  = (const int*)d_in[2];
    const int*   et   = (const int*)d_in[3];
    const float* Wrel = (const float*)d_in[4];
    const float* loopw= (const float*)d_in[5];
    const float* relb = (const float*)d_in[6];
    const float* W1   = (const float*)d_in[7];
    const float* b1   = (const float*)d_in[8];
    const float* W2   = (const float*)d_in[9];
    const float* b2   = (const float*)d_in[10];
    const int E = in_sizes[1];
    float* out = (float*)d_out;

    char* ws = (char*)d_ws;
    u16* WT   = (u16*)(ws);                   //    294,912 B
    u16* W1t  = (u16*)(ws + 294912);          //    131,072 B
    u16* W2t  = (u16*)(ws + 425984);          //     98,304 B
    int* cnt  = (int*)(ws + 524288);          //    400,000 B (reused as cursor)
    int* Off  = (int*)(ws + 924288);          //    400,128 B (NN+1 ints, padded)
    int* bsum = (int*)(ws + 1324416);         //      4,096 B
    int* esrc = (int*)(ws + 1328512);         //  6,400,000 B
    u16* y    = (u16*)(ws + 7728512);         // 230,400,000 B (9 x NN x 128 bf16)
    int* gidx = (int*)(ws + 7728512);         //  6,400,000 B — aliases y head; dead before k_y
    u16* msg  = y + (size_t)8 * NN * DD;      // in-place over y8 slot
    // total required: 238,128,512 B (<= proven-available 243,728,640)
    if (ws_size < 238128512UL) return;

    hipMemsetAsync(cnt, 0, NN * sizeof(int), stream);
    k_prep_w<<<1024, 256, 0, stream>>>(Wrel, loopw, W1, W2, WT, W1t, W2t);
    k_count<<<(E + 255) / 256, 256, 0, stream>>>(et, dst, src, cnt, gidx, E);
    k_scan1<<<NB1, 256, 0, stream>>>(cnt, Off, bsum);
    k_scan2<<<1, 1024, 0, stream>>>(bsum);
    k_scan3<<<NB1, 256, 0, stream>>>(Off, bsum, cnt, E);
    k_scatter<<<(E + 255) / 256, 256, 0, stream>>>(dst, gidx, cnt, esrc, E);
    k_y<<<(NN + 63) / 64, 512, 0, stream>>>(x, WT, y);
    k_gath<<<NN / 32, 256, 0, stream>>>(y, Off, esrc, relb, msg);
    k_fused<<<(NN + 63) / 64, 512, 0, stream>>>(x, msg, W1t, W2t, b1, b2, out);
}

// Round 13
// 504.823 us; speedup vs baseline: 1.0889x; 1.0889x over previous
//
#include <hip/hip_runtime.h>

#define NN 100000
#define DD 128
#define RR 8
#define NSEG (RR*NN)          // 800000 segments (etype*N + dst)
#define NB1 782               // ceil(NSEG/1024)
#define MCAP 3072             // per-block edge cap (8 rel x 64 nodes, Poisson(1024))

typedef unsigned short u16;
typedef __bf16 bf16x8 __attribute__((ext_vector_type(8)));
typedef float f32x4 __attribute__((ext_vector_type(4)));

__device__ __forceinline__ u16 f2bf(float f){
    union { float f; unsigned u; } v; v.f = f;
    unsigned r = v.u + 0x7fffu + ((v.u >> 16) & 1u);
    return (u16)(r >> 16);
}
__device__ __forceinline__ float bf2f(u16 h){
    union { unsigned u; float f; } v; v.u = ((unsigned)h) << 16; return v.f;
}
__device__ __forceinline__ unsigned cvtpk(float lo, float hi){
    unsigned r;
    asm("v_cvt_pk_bf16_f32 %0, %1, %2" : "=v"(r) : "v"(lo), "v"(hi));
    return r;
}
__device__ __forceinline__ float ftanh(float x){
    float e = __expf(2.0f * x);
    return 1.0f - 2.0f / (e + 1.0f);
}
__device__ __forceinline__ bf16x8 ldv(const u16* p){
    return *reinterpret_cast<const bf16x8*>(p);
}
__device__ __forceinline__ void gload_lds16(const void* g, void* l){
    __builtin_amdgcn_global_load_lds(
        (const __attribute__((address_space(1))) void*)g,
        (__attribute__((address_space(3))) void*)l, 16, 0, 0);
}

// ---- prep: cast x to bf16 ----
__global__ void k_cast_x(const float* __restrict__ x, u16* __restrict__ xb, int n){
    int i = (blockIdx.x * 256 + threadIdx.x) * 4;
    if (i >= n) return;
    float4 v = *reinterpret_cast<const float4*>(x + i);
    ushort4 o = make_ushort4(f2bf(v.x), f2bf(v.y), f2bf(v.z), f2bf(v.w));
    *reinterpret_cast<ushort4*>(xb + i) = o;
}

// ---- prep: transpose weights to out-major bf16 ----
__global__ void k_prep_w(const float* __restrict__ Wrel, const float* __restrict__ loopw,
                         const float* __restrict__ W1, const float* __restrict__ W2,
                         u16* __restrict__ WT, u16* __restrict__ W1t, u16* __restrict__ W2t){
    int tid = blockIdx.x * 256 + threadIdx.x;   // grid 1024*256 = 262144 exactly
    if (tid < 131072) {
        int r = tid >> 14, rem = tid & 16383, d = rem >> 7, o = rem & 127;
        WT[(r * 128 + o) * 128 + d] = f2bf(Wrel[tid]);
    } else if (tid < 147456) {
        int i = tid - 131072, d = i >> 7, o = i & 127;
        WT[(8 * 128 + o) * 128 + d] = f2bf(loopw[i]);
    } else if (tid < 212992) {
        int i = tid - 147456, k = i >> 8, n2 = i & 255;
        W1t[n2 * 256 + k] = f2bf(W1[i]);
    } else {
        int i = tid - 212992, k = i >> 7, n2 = i & 127;
        W2t[n2 * 384 + k] = f2bf(W2[i]);
    }
}

// ---- CSR build over (rel,dst) segments ----
__global__ void k_count(const int* __restrict__ et, const int* __restrict__ dst,
                        int* __restrict__ cnt, int* __restrict__ seg, int E){
    int e = blockIdx.x * 256 + threadIdx.x;
    if (e < E){
        int s = et[e] * NN + dst[e];
        seg[e] = s;
        atomicAdd(&cnt[s], 1);
    }
}

__global__ void k_scan1(const int* __restrict__ cnt, int* __restrict__ Off, int* __restrict__ bsum){
    __shared__ int lds[256];
    int t = threadIdx.x;
    int i0 = blockIdx.x * 1024 + t * 4;
    int c0 = (i0 + 0 < NSEG) ? cnt[i0 + 0] : 0;
    int c1 = (i0 + 1 < NSEG) ? cnt[i0 + 1] : 0;
    int c2 = (i0 + 2 < NSEG) ? cnt[i0 + 2] : 0;
    int c3 = (i0 + 3 < NSEG) ? cnt[i0 + 3] : 0;
    int s = c0 + c1 + c2 + c3;
    lds[t] = s; __syncthreads();
    for (int off = 1; off < 256; off <<= 1){
        int v = (t >= off) ? lds[t - off] : 0;
        __syncthreads();
        lds[t] += v;
        __syncthreads();
    }
    int excl = lds[t] - s;
    if (i0 + 0 < NSEG) Off[i0 + 0] = excl; excl += c0;
    if (i0 + 1 < NSEG) Off[i0 + 1] = excl; excl += c1;
    if (i0 + 2 < NSEG) Off[i0 + 2] = excl; excl += c2;
    if (i0 + 3 < NSEG) Off[i0 + 3] = excl;
    if (t == 255) bsum[blockIdx.x] = lds[255];
}

__global__ void k_scan2(int* __restrict__ bsum){
    __shared__ int lds[1024];
    int t = threadIdx.x;
    int v = (t < NB1) ? bsum[t] : 0;
    lds[t] = v; __syncthreads();
    for (int off = 1; off < 1024; off <<= 1){
        int u = (t >= off) ? lds[t - off] : 0;
        __syncthreads();
        lds[t] += u;
        __syncthreads();
    }
    if (t < NB1) bsum[t] = lds[t] - v;
}

__global__ void k_scan3(int* __restrict__ Off, const int* __restrict__ bsum,
                        int* __restrict__ cursor, int E){
    int base = bsum[blockIdx.x];
    int t = threadIdx.x;
    int i0 = blockIdx.x * 1024 + t * 4;
    #pragma unroll
    for (int j = 0; j < 4; ++j){
        int i = i0 + j;
        if (i < NSEG){ int v = Off[i] + base; Off[i] = v; cursor[i] = v; }
    }
    if (blockIdx.x == 0 && t == 0) Off[NSEG] = E;
}

__global__ void k_scatter(const int* __restrict__ seg, const int* __restrict__ src,
                          int* __restrict__ cursor, int* __restrict__ esrc, int E){
    int e = blockIdx.x * 256 + threadIdx.x;
    if (e < E){
        int pos = atomicAdd(&cursor[seg[e]], 1);
        esrc[pos] = src[e];
    }
}

// ---- MEGA: gather-aggregate (LDS, pipelined) -> 9 rel MFMA -> MLP1 -> MLP2 ----
// 64-node tile, 512 threads (8 waves / 16 half-waves), grid 1563.
// LDS = exactly 65536 B:
//   [0,16384)      xt   [64][128] bf16, DMA'd with src-side XOR swizzle
//   B-phase:  offs 8x65 ints @16384; ebase 9 ints @18464; eidx 3136 ints @18560;
//             agg0 @31104 [64][128]; agg1 @47488 [64][128]  (XOR-swizzled)
//   post-B:   msgs [64][128] swz @16384;  mids [64][256] swz @32768
__global__ __launch_bounds__(512, 4) void k_mega(
    const u16* __restrict__ xb, const int* __restrict__ Off, const int* __restrict__ esrc,
    const u16* __restrict__ WT, const u16* __restrict__ W1t, const u16* __restrict__ W2t,
    const float* __restrict__ relb, const float* __restrict__ bb1, const float* __restrict__ bb2,
    float* __restrict__ out)
{
    __shared__ __align__(16) u16 smem[32768];
    u16* xt    = smem;                                  // bytes [0,16384)
    int* offs  = (int*)((char*)smem + 16384);           // 520 ints
    int* ebase = (int*)((char*)smem + 18464);           // 9 ints
    int* eidx  = (int*)((char*)smem + 18560);           // 3136 ints (cap 3072 + slack)
    u16* agg0  = (u16*)((char*)smem + 31104);           // [64][128]
    u16* agg1  = (u16*)((char*)smem + 47488);           // [64][128]
    u16* msgs  = (u16*)((char*)smem + 16384);           // [64][128] swizzled (post-B)
    u16* mids  = (u16*)((char*)smem + 32768);           // [64][256] swizzled (post-B)

    const int tid = threadIdx.x;
    const int w = tid >> 6, lane = tid & 63, l15 = lane & 15, l4 = lane >> 4;
    const int kof = l4 * 8;
    const int swz = (l15 & 7) << 3;      // read-side XOR key (u16 units)
    const int b64 = blockIdx.x * 64;
    const int hw = tid >> 5, lid = tid & 31, c = lid * 4;

    // ---- x-tile DMA (src-side swizzle; verified r8 pattern) ----
    #pragma unroll
    for (int is = 0; is < 2; ++is){
        int W = tid * 16 + is * 8192;
        int row = W >> 8;
        int srow = (b64 + row < NN) ? row : 0;
        int inrow = (W & 255) ^ ((row & 7) << 4);
        gload_lds16((const char*)(xb + (size_t)(b64 + srow) * DD) + inrow, (char*)smem + W);
    }
    // ---- offs: 8 relations x 65 offsets (520 entries, 512 threads -> strided!) ----
    for (int i = tid; i < 520; i += 512){
        int r = i / 65, j = i - r * 65;
        int node = b64 + j; if (node > NN) node = NN;       // clamp: empty segs
        offs[i] = Off[r * NN + node];
    }
    __syncthreads();
    if (tid == 0){
        int b = 0;
        #pragma unroll
        for (int r = 0; r < 8; ++r){ ebase[r] = b; b += offs[r * 65 + 64] - offs[r * 65]; }
        ebase[8] = b;
    }
    __syncthreads();
    const int tot = ebase[8];
    const bool inlds = (tot <= MCAP);
    if (inlds){
        for (int r = 0; r < 8; ++r){
            int o0 = offs[r * 65], n = offs[r * 65 + 64] - o0, eb = ebase[r];
            for (int i = tid; i < n; i += 512) eidx[eb + i] = esrc[o0 + i];
        }
    }
    __syncthreads();

    // ---- gather one relation's 64x128 tile into buf (XOR-swizzled rows) ----
    auto gather = [&](u16* buf, int r){
        const int o0 = offs[r * 65];
        const int eb = ebase[r] - o0;        // eidx index = eb + raw_offset
        #pragma unroll
        for (int j = 0; j < 4; ++j){
            const int sj = hw * 4 + j;
            const int lo = offs[r * 65 + sj], hi = offs[r * 65 + sj + 1];
            const int n = hi - lo;
            float a0 = 0.f, a1 = 0.f, a2 = 0.f, a3 = 0.f;
            if (inlds){
                const int base = eb + lo;
                #pragma unroll
                for (int k = 0; k < 4; ++k){
                    if (k < n){
                        int id = eidx[base + k];
                        ushort4 v = *reinterpret_cast<const ushort4*>(xb + (size_t)id * DD + c);
                        a0 += bf2f(v.x); a1 += bf2f(v.y); a2 += bf2f(v.z); a3 += bf2f(v.w);
                    }
                }
                for (int k = 4; k < n; ++k){
                    int id = eidx[base + k];
                    ushort4 v = *reinterpret_cast<const ushort4*>(xb + (size_t)id * DD + c);
                    a0 += bf2f(v.x); a1 += bf2f(v.y); a2 += bf2f(v.z); a3 += bf2f(v.w);
                }
            } else {
                for (int e = lo; e < hi; ++e){
                    int id = esrc[e];
                    ushort4 v = *reinterpret_cast<const ushort4*>(xb + (size_t)id * DD + c);
                    a0 += bf2f(v.x); a1 += bf2f(v.y); a2 += bf2f(v.z); a3 += bf2f(v.w);
                }
            }
            uint2 p; p.x = cvtpk(a0, a1); p.y = cvtpk(a2, a3);
            *reinterpret_cast<uint2*>(buf + sj * 128 + (c ^ ((sj & 7) << 3))) = p;
        }
    };

    // ---------- phase B: msg = sum_r agg_r @ W_r + x @ loop_w ----------
    f32x4 acc[4];
    #pragma unroll
    for (int mi = 0; mi < 4; ++mi)
        #pragma unroll
        for (int q = 0; q < 4; ++q) acc[mi][q] = 0.f;

    gather(agg0, 0);
    __syncthreads();

    for (int r = 0; r < 8; ++r){
        if (r < 7) gather((r & 1) ? agg0 : agg1, r + 1);   // VMEM flies under MFMAs
        const u16* A = (r & 1) ? agg1 : agg0;
        const u16* B = WT + r * (DD * DD);
        #pragma unroll
        for (int kc = 0; kc < 4; ++kc){
            int cA = (kc * 32 + kof) ^ swz;
            bf16x8 a0 = ldv(A + (l15) * 128 + cA);
            bf16x8 a1 = ldv(A + (16 + l15) * 128 + cA);
            bf16x8 a2 = ldv(A + (32 + l15) * 128 + cA);
            bf16x8 a3 = ldv(A + (48 + l15) * 128 + cA);
            bf16x8 wv = ldv(B + (w * 16 + l15) * DD + kc * 32 + kof);
            acc[0] = __builtin_amdgcn_mfma_f32_16x16x32_bf16(a0, wv, acc[0], 0, 0, 0);
            acc[1] = __builtin_amdgcn_mfma_f32_16x16x32_bf16(a1, wv, acc[1], 0, 0, 0);
            acc[2] = __builtin_amdgcn_mfma_f32_16x16x32_bf16(a2, wv, acc[2], 0, 0, 0);
            acc[3] = __builtin_amdgcn_mfma_f32_16x16x32_bf16(a3, wv, acc[3], 0, 0, 0);
        }
        __syncthreads();
    }
    {   // self-loop from x tile (swizzled reads)
        const u16* B = WT + 8 * (DD * DD);
        #pragma unroll
        for (int kc = 0; kc < 4; ++kc){
            int cA = (kc * 32 + kof) ^ swz;
            bf16x8 a0 = ldv(xt + (l15) * 128 + cA);
            bf16x8 a1 = ldv(xt + (16 + l15) * 128 + cA);
            bf16x8 a2 = ldv(xt + (32 + l15) * 128 + cA);
            bf16x8 a3 = ldv(xt + (48 + l15) * 128 + cA);
            bf16x8 wv = ldv(B + (w * 16 + l15) * DD + kc * 32 + kof);
            acc[0] = __builtin_amdgcn_mfma_f32_16x16x32_bf16(a0, wv, acc[0], 0, 0, 0);
            acc[1] = __builtin_amdgcn_mfma_f32_16x16x32_bf16(a1, wv, acc[1], 0, 0, 0);
            acc[2] = __builtin_amdgcn_mfma_f32_16x16x32_bf16(a2, wv, acc[2], 0, 0, 0);
            acc[3] = __builtin_amdgcn_mfma_f32_16x16x32_bf16(a3, wv, acc[3], 0, 0, 0);
        }
    }

    {   // msgs <- acc + bias (swizzled store; wave owns cols [16w,16w+16))
        int col = w * 16 + l15;
        float bv = relb[col];
        #pragma unroll
        for (int mi = 0; mi < 4; ++mi)
            #pragma unroll
            for (int q = 0; q < 4; ++q){
                int row = mi * 16 + l4 * 4 + q;
                msgs[row * 128 + (col ^ ((row & 7) << 3))] = f2bf(acc[mi][q] + bv);
            }
    }
    __syncthreads();

    // ---------- phase C: mid = tanh([x|msg] @ W1 + b1); cols [32w,32w+32) ----------
    f32x4 acc2[4][2];
    #pragma unroll
    for (int mi = 0; mi < 4; ++mi)
        #pragma unroll
        for (int nj = 0; nj < 2; ++nj)
            #pragma unroll
            for (int q = 0; q < 4; ++q) acc2[mi][nj][q] = 0.f;

    #pragma unroll
    for (int kc = 0; kc < 8; ++kc){
        bf16x8 a[4];
        #pragma unroll
        for (int mi = 0; mi < 4; ++mi){
            int cA = ((kc & 3) * 32 + kof) ^ swz;
            a[mi] = (kc < 4) ? ldv(xt + (mi * 16 + l15) * 128 + cA)
                             : ldv(msgs + (mi * 16 + l15) * 128 + cA);
        }
        #pragma unroll
        for (int nj = 0; nj < 2; ++nj){
            int n2 = w * 32 + nj * 16 + l15;
            bf16x8 wv = ldv(W1t + n2 * 256 + kc * 32 + kof);
            #pragma unroll
            for (int mi = 0; mi < 4; ++mi)
                acc2[mi][nj] = __builtin_amdgcn_mfma_f32_16x16x32_bf16(a[mi], wv, acc2[mi][nj], 0, 0, 0);
        }
    }
    // mids [32768,65536) disjoint from msgs/xt -> no barrier before writes
    #pragma unroll
    for (int nj = 0; nj < 2; ++nj){
        int col = w * 32 + nj * 16 + l15;
        float bv = bb1[col];
        #pragma unroll
        for (int mi = 0; mi < 4; ++mi)
            #pragma unroll
            for (int q = 0; q < 4; ++q){
                int row = mi * 16 + l4 * 4 + q;
                mids[row * 256 + (col ^ ((row & 7) << 3))] = f2bf(ftanh(acc2[mi][nj][q] + bv));
            }
    }
    __syncthreads();

    // ---------- phase D: out = [x|mid] @ W2 + b2; cols [16w,16w+16) ----------
    f32x4 acc3[4];
    #pragma unroll
    for (int mi = 0; mi < 4; ++mi)
        #pragma unroll
        for (int q = 0; q < 4; ++q) acc3[mi][q] = 0.f;

    #pragma unroll
    for (int kc = 0; kc < 12; ++kc){
        bf16x8 a[4];
        #pragma unroll
        for (int mi = 0; mi < 4; ++mi){
            if (kc < 4){
                int cA = (kc * 32 + kof) ^ swz;
                a[mi] = ldv(xt + (mi * 16 + l15) * 128 + cA);
            } else {
                int cA = (((kc - 4) * 32) + kof) ^ swz;
                a[mi] = ldv(mids + (mi * 16 + l15) * 256 + cA);
            }
        }
        bf16x8 wv = ldv(W2t + (w * 16 + l15) * 384 + kc * 32 + kof);
        #pragma unroll
        for (int mi = 0; mi < 4; ++mi)
            acc3[mi] = __builtin_amdgcn_mfma_f32_16x16x32_bf16(a[mi], wv, acc3[mi], 0, 0, 0);
    }

    {
        int col = w * 16 + l15;
        float bv = bb2[col];
        #pragma unroll
        for (int mi = 0; mi < 4; ++mi)
            #pragma unroll
            for (int q = 0; q < 4; ++q){
                int row = b64 + mi * 16 + l4 * 4 + q;
                if (row < NN)
                    __builtin_nontemporal_store(acc3[mi][q] + bv,
                        &out[(size_t)row * DD + col]);
            }
    }
}

extern "C" void kernel_launch(void* const* d_in, const int* in_sizes, int n_in,
                              void* d_out, int out_size, void* d_ws, size_t ws_size,
                              hipStream_t stream){
    const float* x    = (const float*)d_in[0];
    const int*   src  = (const int*)d_in[1];
    const int*   dst  = (const int*)d_in[2];
    const int*   et   = (const int*)d_in[3];
    const float* Wrel = (const float*)d_in[4];
    const float* loopw= (const float*)d_in[5];
    const float* relb = (const float*)d_in[6];
    const float* W1   = (const float*)d_in[7];
    const float* b1   = (const float*)d_in[8];
    const float* W2   = (const float*)d_in[9];
    const float* b2   = (const float*)d_in[10];
    const int E = in_sizes[1];
    float* out = (float*)d_out;

    char* ws = (char*)d_ws;
    u16* xb   = (u16*)(ws);                   // 25,600,000 B
    u16* WT   = (u16*)(ws + 25600000);        //    294,912 B
    u16* W1t  = (u16*)(ws + 25894912);        //    131,072 B
    u16* W2t  = (u16*)(ws + 26025984);        //     98,304 B
    int* cnt  = (int*)(ws + 26124288);        //  3,200,000 B (reused as cursor)
    int* Off  = (int*)(ws + 29324288);        //  3,200,256 B (NSEG+1 ints, padded)
    int* bsum = (int*)(ws + 32524544);        //      4,096 B
    int* esrc = (int*)(ws + 32528640);        //  6,400,000 B
    int* seg  = (int*)(ws + 38928640);        //  6,400,000 B
    // total required: 45,328,640 B
    if (ws_size < 45328640UL) return;

    hipMemsetAsync(cnt, 0, NSEG * sizeof(int), stream);
    k_cast_x<<<12500, 256, 0, stream>>>(x, xb, NN * DD);
    k_prep_w<<<1024, 256, 0, stream>>>(Wrel, loopw, W1, W2, WT, W1t, W2t);
    k_count<<<(E + 255) / 256, 256, 0, stream>>>(et, dst, cnt, seg, E);
    k_scan1<<<NB1, 256, 0, stream>>>(cnt, Off, bsum);
    k_scan2<<<1, 1024, 0, stream>>>(bsum);
    k_scan3<<<NB1, 256, 0, stream>>>(Off, bsum, cnt, E);
    k_scatter<<<(E + 255) / 256, 256, 0, stream>>>(seg, src, cnt, esrc, E);
    k_mega<<<(NN + 63) / 64, 512, 0, stream>>>(xb, Off, esrc, WT, W1t, W2t, relb, b1, b2, out);
}

// Round 14
// 436.978 us; speedup vs baseline: 1.2580x; 1.1553x over previous
//
#include <hip/hip_runtime.h>

#define NN 100000
#define DD 128
#define RR 8
#define NSEG (RR*NN)          // 800000 segments (etype*N + dst)
#define NB1 782               // ceil(NSEG/1024)
#define ECAP 2048             // per-block LDS edge-index cap

typedef unsigned short u16;
typedef __bf16 bf16x8 __attribute__((ext_vector_type(8)));
typedef float f32x4 __attribute__((ext_vector_type(4)));
typedef u16 ushort4e __attribute__((ext_vector_type(4)));
typedef unsigned int uint4e __attribute__((ext_vector_type(4)));

__device__ __forceinline__ u16 f2bf(float f){
    union { float f; unsigned u; } v; v.f = f;
    unsigned r = v.u + 0x7fffu + ((v.u >> 16) & 1u);
    return (u16)(r >> 16);
}
__device__ __forceinline__ float bf2f(u16 h){
    union { unsigned u; float f; } v; v.u = ((unsigned)h) << 16; return v.f;
}
__device__ __forceinline__ float ftanh(float x){
    float e = __expf(2.0f * x);          // inf-safe: x>>0 -> 1, x<<0 -> -1
    return 1.0f - 2.0f / (e + 1.0f);
}
__device__ __forceinline__ bf16x8 ldv(const u16* p){
    return *reinterpret_cast<const bf16x8*>(p);
}
__device__ __forceinline__ void gload_lds16(const void* g, void* l){
    __builtin_amdgcn_global_load_lds(
        (const __attribute__((address_space(1))) void*)g,
        (__attribute__((address_space(3))) void*)l, 16, 0, 0);
}

// ---- fused prep: cast_x | prep_w | count, one launch (overlap + fewer gaps) ----
__global__ void k_prep1(const float* __restrict__ x, u16* __restrict__ xb,
                        const float* __restrict__ Wrel, const float* __restrict__ loopw,
                        const float* __restrict__ W1, const float* __restrict__ W2,
                        u16* __restrict__ WT, u16* __restrict__ W1t, u16* __restrict__ W2t,
                        const int* __restrict__ et, const int* __restrict__ dst,
                        int* __restrict__ cnt, int* __restrict__ seg, int E){
    const int bid = blockIdx.x;
    if (bid < 12500){
        // cast x -> bf16 (12500 * 1024 = 12,800,000 = NN*DD exact)
        int i = (bid * 256 + threadIdx.x) * 4;
        float4 v = *reinterpret_cast<const float4*>(x + i);
        ushort4 o = make_ushort4(f2bf(v.x), f2bf(v.y), f2bf(v.z), f2bf(v.w));
        *reinterpret_cast<ushort4*>(xb + i) = o;
    } else if (bid < 13524){
        // weight transposes (1024 * 256 = 262144 exact)
        int tid = (bid - 12500) * 256 + threadIdx.x;
        if (tid < 131072) {
            int r = tid >> 14, rem = tid & 16383, d = rem >> 7, o = rem & 127;
            WT[(r * 128 + o) * 128 + d] = f2bf(Wrel[tid]);
        } else if (tid < 147456) {
            int i = tid - 131072, d = i >> 7, o = i & 127;
            WT[(8 * 128 + o) * 128 + d] = f2bf(loopw[i]);
        } else if (tid < 212992) {
            int i = tid - 147456, k = i >> 8, n2 = i & 255;
            W1t[n2 * 256 + k] = f2bf(W1[i]);
        } else {
            int i = tid - 212992, k = i >> 7, n2 = i & 127;
            W2t[n2 * 384 + k] = f2bf(W2[i]);
        }
    } else {
        // count + cache combined segment id
        int e = (bid - 13524) * 256 + threadIdx.x;
        if (e < E){
            int s = et[e] * NN + dst[e];
            seg[e] = s;
            atomicAdd(&cnt[s], 1);
        }
    }
}

__global__ void k_scan1(const int* __restrict__ cnt, int* __restrict__ Off, int* __restrict__ bsum){
    __shared__ int lds[256];
    int t = threadIdx.x;
    int i0 = blockIdx.x * 1024 + t * 4;
    int c0 = (i0 + 0 < NSEG) ? cnt[i0 + 0] : 0;
    int c1 = (i0 + 1 < NSEG) ? cnt[i0 + 1] : 0;
    int c2 = (i0 + 2 < NSEG) ? cnt[i0 + 2] : 0;
    int c3 = (i0 + 3 < NSEG) ? cnt[i0 + 3] : 0;
    int s = c0 + c1 + c2 + c3;
    lds[t] = s; __syncthreads();
    for (int off = 1; off < 256; off <<= 1){
        int v = (t >= off) ? lds[t - off] : 0;
        __syncthreads();
        lds[t] += v;
        __syncthreads();
    }
    int excl = lds[t] - s;
    if (i0 + 0 < NSEG) Off[i0 + 0] = excl; excl += c0;
    if (i0 + 1 < NSEG) Off[i0 + 1] = excl; excl += c1;
    if (i0 + 2 < NSEG) Off[i0 + 2] = excl; excl += c2;
    if (i0 + 3 < NSEG) Off[i0 + 3] = excl;
    if (t == 255) bsum[blockIdx.x] = s + lds[t] - s;   // block total (lds[255])
}

// scan3b: per-block redundant prefix over raw block totals (replaces scan2+scan3)
__global__ void k_scan3b(int* __restrict__ Off, const int* __restrict__ bsum,
                         int* __restrict__ cursor, int E){
    __shared__ int lds[256];
    const int bid = blockIdx.x;
    const int t = threadIdx.x;
    int s = 0;
    for (int j = t; j < bid; j += 256) s += bsum[j];   // sum of totals of blocks < bid
    lds[t] = s; __syncthreads();
    #pragma unroll
    for (int off = 128; off > 0; off >>= 1){
        if (t < off) lds[t] += lds[t + off];
        __syncthreads();
    }
    const int base = lds[0];
    int i0 = bid * 1024 + t * 4;
    #pragma unroll
    for (int j = 0; j < 4; ++j){
        int i = i0 + j;
        if (i < NSEG){ int v = Off[i] + base; Off[i] = v; cursor[i] = v; }
    }
    if (bid == 0 && t == 0) Off[NSEG] = E;
}

__global__ void k_scatter(const int* __restrict__ seg, const int* __restrict__ src,
                          int* __restrict__ cursor, int* __restrict__ esrc, int E){
    int e = blockIdx.x * 256 + threadIdx.x;
    if (e < E){
        int pos = atomicAdd(&cursor[seg[e]], 1);
        esrc[pos] = src[e];
    }
}

// ---- block-cooperative gather-aggregate (round-6 verbatim, proven 159 us) ----
__global__ __launch_bounds__(256) void k_agg(
    const u16* __restrict__ xb, const int* __restrict__ Off,
    const int* __restrict__ esrc, u16* __restrict__ agg)
{
    __shared__ int offs[33];
    __shared__ int eidx[ECAP];
    const int tid = threadIdx.x;
    const int s0 = blockIdx.x * 32;        // grid = NSEG/32 exact
    if (tid < 33) offs[tid] = Off[s0 + tid];
    __syncthreads();
    const int base = offs[0];
    const int tot = offs[32] - base;
    const bool inlds = (tot <= ECAP);
    if (inlds){
        for (int i = tid; i < tot; i += 256) eidx[i] = esrc[base + i];
    }
    __syncthreads();

    const int hw = tid >> 5;               // half-wave 0..7
    const int lid = tid & 31;
    const int c = lid * 4;

    #pragma unroll
    for (int j = 0; j < 4; ++j){
        const int sj = hw * 4 + j;         // segment-in-block 0..31
        const int lo = offs[sj] - base;
        const int hi = offs[sj + 1] - base;
        float a0 = 0.f, a1 = 0.f, a2 = 0.f, a3 = 0.f;
        int e = lo;
        if (inlds){
            for (; e + 4 <= hi; e += 4){   // 4 independent rows in flight
                int i0 = eidx[e], i1 = eidx[e+1], i2 = eidx[e+2], i3 = eidx[e+3];
                ushort4 v0 = *reinterpret_cast<const ushort4*>(xb + (size_t)i0 * DD + c);
                ushort4 v1 = *reinterpret_cast<const ushort4*>(xb + (size_t)i1 * DD + c);
                ushort4 v2 = *reinterpret_cast<const ushort4*>(xb + (size_t)i2 * DD + c);
                ushort4 v3 = *reinterpret_cast<const ushort4*>(xb + (size_t)i3 * DD + c);
                a0 += bf2f(v0.x) + bf2f(v1.x) + bf2f(v2.x) + bf2f(v3.x);
                a1 += bf2f(v0.y) + bf2f(v1.y) + bf2f(v2.y) + bf2f(v3.y);
                a2 += bf2f(v0.z) + bf2f(v1.z) + bf2f(v2.z) + bf2f(v3.z);
                a3 += bf2f(v0.w) + bf2f(v1.w) + bf2f(v2.w) + bf2f(v3.w);
            }
            for (; e < hi; ++e){
                int i = eidx[e];
                ushort4 v = *reinterpret_cast<const ushort4*>(xb + (size_t)i * DD + c);
                a0 += bf2f(v.x); a1 += bf2f(v.y); a2 += bf2f(v.z); a3 += bf2f(v.w);
            }
        } else {                           // fallback: oversize block range
            for (; e < hi; ++e){
                int i = esrc[base + e];
                ushort4 v = *reinterpret_cast<const ushort4*>(xb + (size_t)i * DD + c);
                a0 += bf2f(v.x); a1 += bf2f(v.y); a2 += bf2f(v.z); a3 += bf2f(v.w);
            }
        }
        ushort4e o;
        o.x = f2bf(a0); o.y = f2bf(a1); o.z = f2bf(a2); o.w = f2bf(a3);
        __builtin_nontemporal_store(o,
            reinterpret_cast<ushort4e*>(agg + (size_t)(s0 + sj) * DD + c));
    }
}

// ---- fused MFMA (round-7 verbatim, proven 448-total config) ----
// DMA staging into unpadded [64][128] tiles, both-sides XOR swizzle.
// LDS (u16): bufA[0,8192) bufB[8192,16384) msgs[16384,25088);
// mids [64][264] aliases smem+8192. 50176 B -> 3 blk/CU.
__global__ __launch_bounds__(512) void k_fused(
    const u16* __restrict__ xb, const u16* __restrict__ agg,
    const u16* __restrict__ WT, const u16* __restrict__ W1t, const u16* __restrict__ W2t,
    const float* __restrict__ relb, const float* __restrict__ bb1, const float* __restrict__ bb2,
    float* __restrict__ out)
{
    __shared__ __align__(16) u16 smem[25088];
    u16 (*bufA)[128] = (u16(*)[128])(smem);
    u16 (*bufB)[128] = (u16(*)[128])(smem + 8192);
    u16 (*msgs)[136] = (u16(*)[136])(smem + 16384);
    u16 (*mids)[264] = (u16(*)[264])(smem + 8192);

    const int tid = threadIdx.x;
    const int w = tid >> 6;          // wave 0..7
    const int lane = tid & 63;
    const int l15 = lane & 15;
    const int l4 = lane >> 4;        // 0..3
    const int kof = l4 * 8;
    const int swz = (l15 & 7) << 3;  // u16-unit XOR for staged-tile reads
    const int b64 = blockIdx.x * 64;

    const int Wb0 = w * 1024 + (lane << 4);
    auto stage_dma = [&](u16* buf, const u16* grows){
        #pragma unroll
        for (int is = 0; is < 2; ++is){
            int W = Wb0 + is * 8192;
            int row = W >> 8;
            int srcrow = (b64 + row < NN) ? row : 0;
            int inrow = (W & 255) ^ ((row & 7) << 4);
            const char* src = (const char*)(grows + (size_t)srcrow * DD) + inrow;
            gload_lds16(src, (char*)buf + W);
        }
    };

    // ---------- phase B: msg = sum_r agg_r @ W_r + x @ loop_w ----------
    f32x4 acc[4];
    #pragma unroll
    for (int mi = 0; mi < 4; ++mi)
        #pragma unroll
        for (int q = 0; q < 4; ++q) acc[mi][q] = 0.f;

    stage_dma(&bufA[0][0], agg + (size_t)b64 * DD);   // relation 0
    __syncthreads();

    for (int r = 0; r <= 8; ++r){
        if (r < 7)       stage_dma((r & 1) ? &bufA[0][0] : &bufB[0][0],
                                   agg + ((size_t)(r + 1) * NN + b64) * DD);
        else if (r == 7) stage_dma(&bufA[0][0], xb + (size_t)b64 * DD);  // x-tile
        const u16 (*A)[128] = (r & 1) ? bufB : bufA;
        const u16* B = WT + r * (DD * DD);
        #pragma unroll
        for (int kc = 0; kc < 4; ++kc){
            int cA = (kc * 32 + kof) ^ swz;
            bf16x8 a0 = ldv(&A[l15][cA]);
            bf16x8 a1 = ldv(&A[16 + l15][cA]);
            bf16x8 a2 = ldv(&A[32 + l15][cA]);
            bf16x8 a3 = ldv(&A[48 + l15][cA]);
            bf16x8 wv = ldv(B + (w * 16 + l15) * DD + kc * 32 + kof);
            acc[0] = __builtin_amdgcn_mfma_f32_16x16x32_bf16(a0, wv, acc[0], 0, 0, 0);
            acc[1] = __builtin_amdgcn_mfma_f32_16x16x32_bf16(a1, wv, acc[1], 0, 0, 0);
            acc[2] = __builtin_amdgcn_mfma_f32_16x16x32_bf16(a2, wv, acc[2], 0, 0, 0);
            acc[3] = __builtin_amdgcn_mfma_f32_16x16x32_bf16(a3, wv, acc[3], 0, 0, 0);
        }
        __syncthreads();
    }

    {   // msgs <- acc + bias   (wave owns cols [16w, 16w+16))
        int col = w * 16 + l15;
        float bv = relb[col];
        #pragma unroll
        for (int mi = 0; mi < 4; ++mi)
            #pragma unroll
            for (int q = 0; q < 4; ++q)
                msgs[mi * 16 + l4 * 4 + q][col] = f2bf(acc[mi][q] + bv);
    }
    __syncthreads();

    // ---------- phase C: mid = tanh([x|msg] @ W1 + b1) ----------
    f32x4 acc2[4][2];
    #pragma unroll
    for (int mi = 0; mi < 4; ++mi)
        #pragma unroll
        for (int nj = 0; nj < 2; ++nj)
            #pragma unroll
            for (int q = 0; q < 4; ++q) acc2[mi][nj][q] = 0.f;

    #pragma unroll
    for (int kc = 0; kc < 8; ++kc){
        bf16x8 a[4];
        #pragma unroll
        for (int mi = 0; mi < 4; ++mi)
            a[mi] = (kc < 4) ? ldv(&bufA[mi * 16 + l15][(kc * 32 + kof) ^ swz])
                             : ldv(&msgs[mi * 16 + l15][(kc - 4) * 32 + kof]);
        #pragma unroll
        for (int nj = 0; nj < 2; ++nj){
            int n2 = w * 32 + nj * 16 + l15;
            bf16x8 wv = ldv(W1t + n2 * 256 + kc * 32 + kof);
            #pragma unroll
            for (int mi = 0; mi < 4; ++mi)
                acc2[mi][nj] = __builtin_amdgcn_mfma_f32_16x16x32_bf16(a[mi], wv, acc2[mi][nj], 0, 0, 0);
        }
    }
    __syncthreads();   // all reads of msgs/bufB region done before mids overwrites it
    #pragma unroll
    for (int nj = 0; nj < 2; ++nj){
        int col = w * 32 + nj * 16 + l15;
        float bv = bb1[col];
        #pragma unroll
        for (int mi = 0; mi < 4; ++mi)
            #pragma unroll
            for (int q = 0; q < 4; ++q)
                mids[mi * 16 + l4 * 4 + q][col] = f2bf(ftanh(acc2[mi][nj][q] + bv));
    }
    __syncthreads();

    // ---------- phase D: out = [x|mid] @ W2 + b2 ----------
    f32x4 acc3[4];
    #pragma unroll
    for (int mi = 0; mi < 4; ++mi)
        #pragma unroll
        for (int q = 0; q < 4; ++q) acc3[mi][q] = 0.f;

    #pragma unroll
    for (int kc = 0; kc < 12; ++kc){
        bf16x8 a[4];
        #pragma unroll
        for (int mi = 0; mi < 4; ++mi)
            a[mi] = (kc < 4) ? ldv(&bufA[mi * 16 + l15][(kc * 32 + kof) ^ swz])
                             : ldv(&mids[mi * 16 + l15][(kc - 4) * 32 + kof]);
        bf16x8 wv = ldv(W2t + (w * 16 + l15) * 384 + kc * 32 + kof);
        #pragma unroll
        for (int mi = 0; mi < 4; ++mi)
            acc3[mi] = __builtin_amdgcn_mfma_f32_16x16x32_bf16(a[mi], wv, acc3[mi], 0, 0, 0);
    }

    {
        int col = w * 16 + l15;
        float bv = bb2[col];
        #pragma unroll
        for (int mi = 0; mi < 4; ++mi)
            #pragma unroll
            for (int q = 0; q < 4; ++q){
                int row = b64 + mi * 16 + l4 * 4 + q;
                if (row < NN)
                    __builtin_nontemporal_store(acc3[mi][q] + bv,
                        &out[(size_t)row * DD + col]);
            }
    }
}

extern "C" void kernel_launch(void* const* d_in, const int* in_sizes, int n_in,
                              void* d_out, int out_size, void* d_ws, size_t ws_size,
                              hipStream_t stream){
    const float* x    = (const float*)d_in[0];
    const int*   src  = (const int*)d_in[1];
    const int*   dst  = (const int*)d_in[2];
    const int*   et   = (const int*)d_in[3];
    const float* Wrel = (const float*)d_in[4];
    const float* loopw= (const float*)d_in[5];
    const float* relb = (const float*)d_in[6];
    const float* W1   = (const float*)d_in[7];
    const float* b1   = (const float*)d_in[8];
    const float* W2   = (const float*)d_in[9];
    const float* b2   = (const float*)d_in[10];
    const int E = in_sizes[1];
    float* out = (float*)d_out;

    char* ws = (char*)d_ws;
    u16* xb   = (u16*)(ws);                   // 25,600,000 B
    u16* WT   = (u16*)(ws + 25600000);        //    294,912 B
    u16* W1t  = (u16*)(ws + 25894912);        //    131,072 B
    u16* W2t  = (u16*)(ws + 26025984);        //     98,304 B
    int* cnt  = (int*)(ws + 26124288);        //  3,200,000 B (reused as cursor)
    int* Off  = (int*)(ws + 29324288);        //  3,200,256 B (NSEG+1 ints, padded)
    int* bsum = (int*)(ws + 32524544);        //      4,096 B
    int* esrc = (int*)(ws + 32528640);        //  6,400,000 B
    u16* agg  = (u16*)(ws + 38928640);        // 204,800,000 B
    int* seg  = (int*)(ws + 38928640);        // 6,400,000 B — aliases agg head; dead before k_agg writes
    // total required: 243,728,640 B
    if (ws_size < 243728640UL) return;

    const int gprep = 13524 + (E + 255) / 256;
    hipMemsetAsync(cnt, 0, NSEG * sizeof(int), stream);
    k_prep1<<<gprep, 256, 0, stream>>>(x, xb, Wrel, loopw, W1, W2, WT, W1t, W2t,
                                       et, dst, cnt, seg, E);
    k_scan1<<<NB1, 256, 0, stream>>>(cnt, Off, bsum);
    k_scan3b<<<NB1, 256, 0, stream>>>(Off, bsum, cnt, E);
    k_scatter<<<(E + 255) / 256, 256, 0, stream>>>(seg, src, cnt, esrc, E);
    k_agg<<<NSEG / 32, 256, 0, stream>>>(xb, Off, esrc, agg);
    k_fused<<<(NN + 63) / 64, 512, 0, stream>>>(xb, agg, WT, W1t, W2t, relb, b1, b2, out);
}